// Round 19
// baseline (136.463 us; speedup 1.0000x reference)
//
#include <hip/hip_runtime.h>

#define NDIM 2048
#define FDIM 64
#define KDIM 8
#define BDIM 32
#define TILE 64
#define BFROW 72   // bf16 elems per staging row (64 + 8 pad)
#define FROW  68   // f32 elems per epilogue-panel row (64 + 4 pad)

typedef __attribute__((ext_vector_type(8))) short short8;
typedef __attribute__((ext_vector_type(4))) float f32x4;

static __device__ __forceinline__ unsigned short f2bf(float x) {
    unsigned u = __float_as_uint(x);                 // RNE to bf16
    return (unsigned short)((u + 0x7fffu + ((u >> 16) & 1u)) >> 16);
}

// ---------------------------------------------------------------------------
// R19: SYMMETRY exploit on the R8/R16-proven recipe. out[b] is symmetric
// (cov_k symmetric), so only 528 tiles (32 diag + 496 strictly-upper 64x64)
// are computed; off-diagonal blocks scatter each mixed value TWICE (P[rl][cl]
// and PT[cl][rl]) and store both the tile and its transpose with row-
// contiguous 256-B-segment NT stores. Store traffic unchanged; cov work
// (staging+MFMA+barriers) halves chip-wide. Diagonal blocks (ids 0..31,
// dispatched first) store half as much -> finish early -> the 16 blocks
// beyond 2/CU residency backfill mid-kernel (no tail penalty).
// bf16 cov[x][y] == cov[y][x] bitwise (same f-order) -> absmax unchanged.
// Proven invariants: staged LDS cov (R17), scalar mix (R6/R7/R9 miscompile),
// lgkm-only barriers (R8), NT stores (R16), no outer tile loop (R15 spill).
// ---------------------------------------------------------------------------
__global__ __launch_bounds__(256, 2) void rfm_fused_mfma(
    const float* __restrict__ p, const float* __restrict__ L,
    const float* __restrict__ sr, float* __restrict__ out)
{
    __shared__ float pl[BDIM * KDIM];
    __shared__ __align__(16) char smem[4 * TILE * FROW * 4];   // 69632 B

    unsigned short* const An = (unsigned short*)smem;        // [64][72] bf16
    unsigned short* const Am = An + TILE * BFROW;
    float* const P0 = (float*)smem;                          // [64][68] f32 x4
    float* const T0 = P0 + TILE * FROW;
    float* const P1 = T0 + TILE * FROW;
    float* const T1 = P1 + TILE * FROW;

    // ---- tile decode: ids 0..31 diagonal, 32..527 strictly-upper ----
    const int id = blockIdx.x;
    int r, c;
    if (id < 32) { r = id; c = id; }
    else {
        int i = id - 32, rr = 0;
        while (i >= 31 - rr) { i -= 31 - rr; ++rr; }   // row rr has 31-rr tiles
        r = rr; c = rr + 1 + i;
    }
    const int n0 = r * TILE;
    const int m0 = c * TILE;
    const bool diag = (r == c);

    const int t  = threadIdx.x;
    const int lane = t & 63;
    const int w   = t >> 6;        // wave 0..3
    const int wr  = w >> 1;        // n-side 32-block
    const int wc  = w & 1;         // m-side 32-block
    const int l15 = lane & 15;
    const int l4  = lane >> 4;     // 0..3

    pl[t] = p[t];                  // covered by first __syncthreads below

    f32x4 acc[KDIM][2][2];
    #pragma unroll
    for (int k = 0; k < KDIM; ++k)
        #pragma unroll
        for (int ti = 0; ti < 2; ++ti)
            #pragma unroll
            for (int tj = 0; tj < 2; ++tj)
                acc[k][ti][tj] = (f32x4){0.f, 0.f, 0.f, 0.f};

    // ---- 1) cov phase (VERBATIM R8: staged bf16 LDS + MFMA) ----
    #pragma unroll
    for (int k = 0; k < KDIM; ++k) {
        const float* Lk = L + (size_t)k * (NDIM * FDIM);

        #pragma unroll
        for (int rq = 0; rq < 4; ++rq) {
            const int idx = t + rq * 256;
            const int row = idx >> 4;          // 16 float4 per row
            const int fc  = (idx & 15) << 2;
            const float4 va = *(const float4*)&Lk[(size_t)(n0 + row) * FDIM + fc];
            const float4 vb = *(const float4*)&Lk[(size_t)(m0 + row) * FDIM + fc];
            ushort4 ua, ub;
            ua.x = f2bf(va.x); ua.y = f2bf(va.y); ua.z = f2bf(va.z); ua.w = f2bf(va.w);
            ub.x = f2bf(vb.x); ub.y = f2bf(vb.y); ub.z = f2bf(vb.z); ub.w = f2bf(vb.w);
            *(ushort4*)&An[row * BFROW + fc] = ua;
            *(ushort4*)&Am[row * BFROW + fc] = ub;
        }
        __syncthreads();

        short8 af[2][2], bv[2][2];
        #pragma unroll
        for (int ti = 0; ti < 2; ++ti)
            #pragma unroll
            for (int s = 0; s < 2; ++s) {
                af[ti][s] = *(const short8*)
                    &An[(wr * 32 + ti * 16 + l15) * BFROW + s * 32 + l4 * 8];
                bv[ti][s] = *(const short8*)
                    &Am[(wc * 32 + ti * 16 + l15) * BFROW + s * 32 + l4 * 8];
            }
        #pragma unroll
        for (int ti = 0; ti < 2; ++ti)
            #pragma unroll
            for (int tj = 0; tj < 2; ++tj)
                #pragma unroll
                for (int s = 0; s < 2; ++s)
                    acc[k][ti][tj] = __builtin_amdgcn_mfma_f32_16x16x32_bf16(
                        af[ti][s], bv[tj][s], acc[k][ti][tj], 0, 0, 0);
        __syncthreads();   // panels consumed; next k (or epilogue) may overwrite
    }

    // Diagonal sr^2 (verbatim R8): C/D map row = l4*4+reg, col = l15.
    if (diag && wr == wc) {
        #pragma unroll
        for (int k = 0; k < KDIM; ++k)
            #pragma unroll
            for (int ti = 0; ti < 2; ++ti)
                #pragma unroll
                for (int reg = 0; reg < 4; ++reg) {
                    const int row = l4 * 4 + reg;
                    if (row == l15) {
                        const float q = sr[k * NDIM + n0 + wr * 32 + ti * 16 + row];
                        acc[k][ti][ti][reg] += q * q;
                    }
                }
    }

    // ---- 2) epilogue: 2 planes/pass x 16 passes; P + (off-diag) PT ----
    const size_t NN = (size_t)NDIM * NDIM;
    const int tx = t & 15;
    const int ty = t >> 4;

    #pragma unroll 1
    for (int b = 0; b < BDIM; b += 2) {
        float pa[KDIM], pb[KDIM];
        #pragma unroll
        for (int k = 0; k < KDIM; ++k) {
            pa[k] = pl[b * KDIM + k];
            pb[k] = pl[(b + 1) * KDIM + k];
        }
        // mix (SCALAR FMAs) + scatter to P (and PT when off-diagonal)
        #pragma unroll
        for (int ti = 0; ti < 2; ++ti)
            #pragma unroll
            for (int tj = 0; tj < 2; ++tj)
                #pragma unroll
                for (int reg = 0; reg < 4; ++reg) {
                    const int rl = wr * 32 + ti * 16 + l4 * 4 + reg;
                    const int cl = wc * 32 + tj * 16 + l15;
                    float va = 0.0f, vb = 0.0f;
                    #pragma unroll
                    for (int k = 0; k < KDIM; ++k) {
                        va += pa[k] * acc[k][ti][tj][reg];
                        vb += pb[k] * acc[k][ti][tj][reg];
                    }
                    P0[rl * FROW + cl] = va;
                    P1[rl * FROW + cl] = vb;
                    if (!diag) {
                        T0[cl * FROW + rl] = va;
                        T1[cl * FROW + rl] = vb;
                    }
                }
        asm volatile("s_waitcnt lgkmcnt(0)" ::: "memory");  // my ds_writes done
        __builtin_amdgcn_s_barrier();                        // all writes done
        __builtin_amdgcn_sched_barrier(0);

        // readback rows + NT stores (4 x 256-B segments per wave-inst)
        #pragma unroll
        for (int q = 0; q < 4; ++q) {
            const int row = ty + 16 * q;
            const f32x4 wa = *(const f32x4*)&P0[row * FROW + tx * 4];
            const f32x4 wb = *(const f32x4*)&P1[row * FROW + tx * 4];
            float* dst = out + (size_t)(n0 + row) * NDIM + m0 + tx * 4;
            __builtin_nontemporal_store(wa, (f32x4*)(dst + (size_t)b * NN));
            __builtin_nontemporal_store(wb, (f32x4*)(dst + (size_t)(b + 1) * NN));
        }
        if (!diag) {
            #pragma unroll
            for (int q = 0; q < 4; ++q) {
                const int row = ty + 16 * q;
                const f32x4 wa = *(const f32x4*)&T0[row * FROW + tx * 4];
                const f32x4 wb = *(const f32x4*)&T1[row * FROW + tx * 4];
                float* dst = out + (size_t)(m0 + row) * NDIM + n0 + tx * 4;
                __builtin_nontemporal_store(wa, (f32x4*)(dst + (size_t)b * NN));
                __builtin_nontemporal_store(wb, (f32x4*)(dst + (size_t)(b + 1) * NN));
            }
        }
        asm volatile("s_waitcnt lgkmcnt(0)" ::: "memory");  // my ds_reads done
        __builtin_amdgcn_s_barrier();                        // safe to overwrite
        __builtin_amdgcn_sched_barrier(0);
    }
}

extern "C" void kernel_launch(void* const* d_in, const int* in_sizes, int n_in,
                              void* d_out, int out_size, void* d_ws, size_t ws_size,
                              hipStream_t stream)
{
    const float* p  = (const float*)d_in[0];   // (B,K) = (32,8)
    const float* L  = (const float*)d_in[1];   // (K,N,F) = (8,2048,64)
    const float* sr = (const float*)d_in[2];   // (K,N)   = (8,2048)
    float* out = (float*)d_out;                // (B,N,N) = (32,2048,2048)

    hipLaunchKernelGGL(rfm_fused_mfma, dim3(528), dim3(256), 0, stream,
                       p, L, sr, out);        // 32 diag + 496 upper tiles
}

// Round 20
// 111.833 us; speedup vs baseline: 1.2202x; 1.2202x over previous
//
#include <hip/hip_runtime.h>

#define NDIM 2048
#define FDIM 64
#define KDIM 8
#define BDIM 32
#define TN   16     // tile rows (n)
#define TM   128    // tile cols (m) -> acc[8][2] = 64 VGPR (spill headroom)
#define BFROW 72    // bf16 elems per staging row (64 + 8 pad)
#define PROW  132   // f32 elems per epilogue-panel row (128 + 4)
#define PLANES 4    // b-planes per epilogue pass
#define NTILE 4     // tiles per persistent block (512 blocks = 2/CU, 1 round)

typedef __attribute__((ext_vector_type(8))) short short8;
typedef __attribute__((ext_vector_type(4))) float f32x4;

static __device__ __forceinline__ unsigned short f2bf(float x) {
    unsigned u = __float_as_uint(x);                 // RNE to bf16
    return (unsigned short)((u + 0x7fffu + ((u >> 16) & 1u)) >> 16);
}

// ---------------------------------------------------------------------------
// R20: persistent retry (R15's bubble theory) with HALVED register pressure.
// R15 spilled (acc=128 VGPR + tile loop -> VGPR_Count 128 + 133MB scratch);
// here tile = 16x128 so acc[8][2] f32x4 = 64 VGPR, total live ~120. Grid 512
// (exactly 2 blocks/CU, ONE residency round) x NTILE=4 tiles each: the cov
// bubble is paid once, then tile t+1's cov overlaps tile t's in-flight NT
// stores (epilogue barriers are lgkm-only; stores never drained).
// Per-tile body = R16-proven recipe: staged bf16 LDS cov + MFMA (full
// k-unroll, static acc idx), SCALAR mix only (f32x4 vector-mix of acc =
// proven miscompile R6/R7/R9), LDS scatter -> row readback (2x512-B segments
// per wave-inst; >=256B proven rate-identical), nontemporal stores.
// ---------------------------------------------------------------------------
__global__ __launch_bounds__(256, 2) void rfm_fused_mfma(
    const float* __restrict__ p, const float* __restrict__ L,
    const float* __restrict__ sr, float* __restrict__ out)
{
    __shared__ float pl[BDIM * KDIM];
    __shared__ __align__(16) char smem[PLANES * TN * PROW * 4];   // 33792 B

    unsigned short* const An = (unsigned short*)smem;       // [TN][BFROW] bf16
    unsigned short* const Am = An + TN * BFROW;             // [TM][BFROW] bf16
    float* const Parr0 = (float*)smem;                      // 4 panels [TN][PROW]
    float* const Parr1 = Parr0 + TN * PROW;
    float* const Parr2 = Parr1 + TN * PROW;
    float* const Parr3 = Parr2 + TN * PROW;

    const int t  = threadIdx.x;
    const int lane = t & 63;
    const int w   = t >> 6;        // wave 0..3: cols w*32..w*32+31
    const int l15 = lane & 15;
    const int l4  = lane >> 4;     // 0..3

    pl[t] = p[t];                  // covered by the first cov __syncthreads

    #pragma unroll 1
    for (int tt = 0; tt < NTILE; ++tt) {
        const int tile = (int)blockIdx.x + tt * 512;   // 0..2047
        const int m0 = (tile & 15) * TM;
        const int n0 = (tile >> 4) * TN;

        f32x4 acc[KDIM][2];
        #pragma unroll
        for (int k = 0; k < KDIM; ++k)
            #pragma unroll
            for (int j = 0; j < 2; ++j) acc[k][j] = (f32x4){0.f, 0.f, 0.f, 0.f};

        // ---- 1) cov phase: staged bf16 LDS + MFMA (R16 pattern) ----
        #pragma unroll
        for (int k = 0; k < KDIM; ++k) {
            const float* Lk = L + (size_t)k * (NDIM * FDIM);

            // An: 16 rows x 16 float4 (1/thread)
            {
                const int row = t >> 4;
                const int fc  = (t & 15) << 2;
                const float4 va = *(const float4*)&Lk[(size_t)(n0 + row) * FDIM + fc];
                ushort4 ua;
                ua.x = f2bf(va.x); ua.y = f2bf(va.y); ua.z = f2bf(va.z); ua.w = f2bf(va.w);
                *(ushort4*)&An[row * BFROW + fc] = ua;
            }
            // Am: 128 rows x 16 float4 = 2048 float4 (8/thread)
            #pragma unroll
            for (int r = 0; r < 8; ++r) {
                const int idx = t + r * 256;
                const int row = idx >> 4;
                const int fc  = (idx & 15) << 2;
                const float4 vb = *(const float4*)&Lk[(size_t)(m0 + row) * FDIM + fc];
                ushort4 ub;
                ub.x = f2bf(vb.x); ub.y = f2bf(vb.y); ub.z = f2bf(vb.z); ub.w = f2bf(vb.w);
                *(ushort4*)&Am[row * BFROW + fc] = ub;
            }
            __syncthreads();

            short8 af[2], bv[2][2];
            #pragma unroll
            for (int s = 0; s < 2; ++s)
                af[s] = *(const short8*)&An[l15 * BFROW + s * 32 + l4 * 8];
            #pragma unroll
            for (int j = 0; j < 2; ++j)
                #pragma unroll
                for (int s = 0; s < 2; ++s)
                    bv[j][s] = *(const short8*)
                        &Am[(w * 32 + j * 16 + l15) * BFROW + s * 32 + l4 * 8];
            #pragma unroll
            for (int j = 0; j < 2; ++j)
                #pragma unroll
                for (int s = 0; s < 2; ++s)
                    acc[k][j] = __builtin_amdgcn_mfma_f32_16x16x32_bf16(
                        af[s], bv[j][s], acc[k][j], 0, 0, 0);
            __syncthreads();   // panels consumed; next k / epilogue may reuse
        }

        // Diagonal: D row = n-local = l4*4+reg, col = m-local = w*32+j*16+l15.
        #pragma unroll
        for (int j = 0; j < 2; ++j)
            #pragma unroll
            for (int reg = 0; reg < 4; ++reg) {
                const int gn = n0 + l4 * 4 + reg;
                const int gm = m0 + w * 32 + j * 16 + l15;
                if (gn == gm) {
                    #pragma unroll
                    for (int k = 0; k < KDIM; ++k) {
                        const float q = sr[k * NDIM + gn];
                        acc[k][j][reg] += q * q;
                    }
                }
            }

        // ---- 2) epilogue: 4 planes/pass x 8 passes (R16 shape, NT stores) ----
        const size_t NN = (size_t)NDIM * NDIM;
        float* const Parr[PLANES] = { Parr0, Parr1, Parr2, Parr3 };
        const int scr = l4 * 4;                 // scatter row base (+reg)
        const int scc = w * 32 + l15;           // scatter col base (+j*16)
        const int rbrow = t >> 5;               // readback row 0..7 (and +8)
        const int rbc4  = (t & 31) * 4;         // readback col 0..124
        float* const obase = out + (size_t)n0 * NDIM + m0 + rbc4;

        #pragma unroll 1
        for (int b = 0; b < BDIM; b += PLANES) {
            // mix (SCALAR FMAs, static acc indices) + scatter
            #pragma unroll
            for (int u = 0; u < PLANES; ++u) {
                float pb[KDIM];
                #pragma unroll
                for (int k = 0; k < KDIM; ++k) pb[k] = pl[(b + u) * KDIM + k];
                float* const Pu = Parr[u];
                #pragma unroll
                for (int j = 0; j < 2; ++j)
                    #pragma unroll
                    for (int reg = 0; reg < 4; ++reg) {
                        float v = 0.0f;
                        #pragma unroll
                        for (int k = 0; k < KDIM; ++k)
                            v += pb[k] * acc[k][j][reg];
                        Pu[(scr + reg) * PROW + scc + j * 16] = v;
                    }
            }
            asm volatile("s_waitcnt lgkmcnt(0)" ::: "memory");  // ds_writes done
            __builtin_amdgcn_s_barrier();
            __builtin_amdgcn_sched_barrier(0);

            // readback + NT stores: rows rbrow and rbrow+8 per plane
            #pragma unroll
            for (int u = 0; u < PLANES; ++u) {
                const float* const Pu = Parr[u];
                const size_t boff = (size_t)(b + u) * NN;
                #pragma unroll
                for (int rr = 0; rr < 2; ++rr) {
                    const int row = rbrow + 8 * rr;
                    const f32x4 wv = *(const f32x4*)&Pu[row * PROW + rbc4];
                    __builtin_nontemporal_store(wv,
                        (f32x4*)(obase + boff + (size_t)row * NDIM));
                }
            }
            asm volatile("s_waitcnt lgkmcnt(0)" ::: "memory");  // ds_reads done
            __builtin_amdgcn_s_barrier();            // safe to overwrite / next tile
            __builtin_amdgcn_sched_barrier(0);
        }
        // tile t+1's staging is ordered after all LDS reads by the last
        // barrier; its global NT stores remain in flight underneath.
    }
}

extern "C" void kernel_launch(void* const* d_in, const int* in_sizes, int n_in,
                              void* d_out, int out_size, void* d_ws, size_t ws_size,
                              hipStream_t stream)
{
    const float* p  = (const float*)d_in[0];   // (B,K) = (32,8)
    const float* L  = (const float*)d_in[1];   // (K,N,F) = (8,2048,64)
    const float* sr = (const float*)d_in[2];   // (K,N)   = (8,2048)
    float* out = (float*)d_out;                // (B,N,N) = (32,2048,2048)

    hipLaunchKernelGGL(rfm_fused_mfma, dim3(512), dim3(256), 0, stream,
                       p, L, sr, out);
}